// Round 8
// baseline (210.858 us; speedup 1.0000x reference)
//
#include <hip/hip_runtime.h>
#include <math.h>

#define HIDDEN 1024
#define NH 16
#define NKV 4
#define HD 64
#define BS_ 2
#define SEQ_ 2048
#define WIN 1534   // allowed iff k - q <= 1534
#define LOG2E 1.4426950408889634f

typedef unsigned short u16;
typedef short short8 __attribute__((ext_vector_type(8)));
typedef float f32x4 __attribute__((ext_vector_type(4)));
typedef float f32x16 __attribute__((ext_vector_type(16)));
typedef u16 u16x4 __attribute__((ext_vector_type(4)));

__device__ __forceinline__ u16 f2bf(float f) {
    unsigned u = __float_as_uint(f);
    u += 0x7fff + ((u >> 16) & 1);      // RNE
    return (u16)(u >> 16);
}

// pack two f32 -> two bf16 (truncation) in ONE v_perm_b32
__device__ __forceinline__ unsigned pk_trunc(float lo, float hi) {
    return __builtin_amdgcn_perm(__float_as_uint(hi), __float_as_uint(lo), 0x07060302u);
}

__device__ __forceinline__ void async_ld16(const u16* g, u16* l) {
    __builtin_amdgcn_global_load_lds(
        (const __attribute__((address_space(1))) unsigned int*)g,
        (__attribute__((address_space(3))) unsigned int*)l, 16, 0, 0);
}

// ---------------- cast fp32 -> bf16 (X + 4 weights) and pre-scale amask ----------------
// amask scaled by -10000*log2(e): attn uses exp2 directly.
__global__ __launch_bounds__(256) void cast6(
    const float* __restrict__ x, const float* __restrict__ wq,
    const float* __restrict__ wk, const float* __restrict__ wv,
    const float* __restrict__ wo, const float* __restrict__ amask,
    u16* __restrict__ xb, u16* __restrict__ wqb, u16* __restrict__ wkb,
    u16* __restrict__ wvb, u16* __restrict__ wob, float* __restrict__ ams)
{
    int seg = blockIdx.y;
    int i = (blockIdx.x * 256 + threadIdx.x) * 4;
    if (seg == 5) {
        if (i >= BS_ * SEQ_) return;
        const float sc = -10000.0f * LOG2E;
        float4 v = *(const float4*)(amask + i);
        float4 o = make_float4(v.x * sc, v.y * sc, v.z * sc, v.w * sc);
        *(float4*)(ams + i) = o;
        return;
    }
    const float* srcs[5] = {x, wq, wk, wv, wo};
    u16* dsts[5] = {xb, wqb, wkb, wvb, wob};
    const int ns[5] = {4194304, 1048576, 262144, 262144, 1048576};
    if (i >= ns[seg]) return;
    float4 v = *(const float4*)(srcs[seg] + i);
    u16x4 o = {f2bf(v.x), f2bf(v.y), f2bf(v.z), f2bf(v.w)};
    *(u16x4*)(dsts[seg] + i) = o;
}

// ---------------- fused QKV MFMA GEMM ----------------
// grid (12, 32): bx<8 -> Q, bx<10 -> K, else V. 128x128 tile, BK=32.
// Q: bias+RoPE, pre-scaled by 0.125*log2(e), bf16 head-major [b][h][s][64]
// K: bias+RoPE bf16 head-major; V: bias + bf16 V^T [b][hk][d][SEQ].
__global__ __launch_bounds__(256) void gemm_qkv(
    const u16* __restrict__ Xb, const u16* __restrict__ Wqb,
    const u16* __restrict__ Wkb, const u16* __restrict__ Wvb,
    const float* __restrict__ bq, const float* __restrict__ bk,
    const float* __restrict__ bv,
    u16* __restrict__ Qp, u16* __restrict__ Kp, u16* __restrict__ Vtp)
{
    __shared__ u16 sA[128 * 32];
    __shared__ u16 sB[128 * 32];
    int tid = threadIdx.x, lane = tid & 63, wave = tid >> 6;
    int col = lane & 15, l4 = lane >> 4;
    int bx = blockIdx.x, m0 = blockIdx.y * 128;
    const u16* Bsrc; const float* bias; int n0, mode;
    if (bx < 8)       { mode = 0; Bsrc = Wqb; bias = bq; n0 = bx * 128; }
    else if (bx < 10) { mode = 1; Bsrc = Wkb; bias = bk; n0 = (bx - 8) * 128; }
    else              { mode = 2; Bsrc = Wvb; bias = bv; n0 = (bx - 10) * 128; }

    int i0 = tid, i1 = tid + 256;
    const u16* ga0 = Xb + (size_t)(m0 + (i0 >> 2)) * HIDDEN + (i0 & 3) * 8;
    const u16* ga1 = Xb + (size_t)(m0 + (i1 >> 2)) * HIDDEN + (i1 & 3) * 8;
    const u16* gb0 = Bsrc + (size_t)(n0 + (i0 >> 2)) * HIDDEN + (i0 & 3) * 8;
    const u16* gb1 = Bsrc + (size_t)(n0 + (i1 >> 2)) * HIDDEN + (i1 & 3) * 8;
    u16* la0 = &sA[wave * 512];
    u16* la1 = &sA[2048 + wave * 512];
    u16* lb0 = &sB[wave * 512];
    u16* lb1 = &sB[2048 + wave * 512];

    f32x4 acc[4][4];
    #pragma unroll
    for (int i = 0; i < 4; ++i)
        #pragma unroll
        for (int j = 0; j < 4; ++j) acc[i][j] = (f32x4){0.f, 0.f, 0.f, 0.f};
    int mh = (wave & 1) * 64, nh = (wave >> 1) * 64;

    for (int k0 = 0; k0 < HIDDEN; k0 += 32) {
        __syncthreads();
        async_ld16(ga0, la0); async_ld16(ga1, la1);
        async_ld16(gb0, lb0); async_ld16(gb1, lb1);
        ga0 += 32; ga1 += 32; gb0 += 32; gb1 += 32;
        __syncthreads();
        short8 af[4], bf[4];
        #pragma unroll
        for (int mi = 0; mi < 4; ++mi)
            af[mi] = *(short8*)&sA[(mh + mi * 16 + col) * 32 + l4 * 8];
        #pragma unroll
        for (int ni = 0; ni < 4; ++ni)
            bf[ni] = *(short8*)&sB[(nh + ni * 16 + col) * 32 + l4 * 8];
        #pragma unroll
        for (int mi = 0; mi < 4; ++mi)
            #pragma unroll
            for (int ni = 0; ni < 4; ++ni)
                acc[mi][ni] = __builtin_amdgcn_mfma_f32_16x16x32_bf16(af[mi], bf[ni], acc[mi][ni], 0, 0, 0);
    }

    float bcol[4];
    #pragma unroll
    for (int ni = 0; ni < 4; ++ni) bcol[ni] = bias[n0 + nh + ni * 16 + col];

    if (mode == 2) {
        // V^T bf16: [b][hk][d][SEQ]; s contiguous over r -> b64 stores
        #pragma unroll
        for (int mi = 0; mi < 4; ++mi) {
            int m = m0 + mh + mi * 16 + l4 * 4;
            int b = m >> 11, s = m & 2047;
            #pragma unroll
            for (int ni = 0; ni < 4; ++ni) {
                int dg = n0 + nh + ni * 16 + col;
                u16x4 pk = {f2bf(acc[mi][ni][0] + bcol[ni]), f2bf(acc[mi][ni][1] + bcol[ni]),
                            f2bf(acc[mi][ni][2] + bcol[ni]), f2bf(acc[mi][ni][3] + bcol[ni])};
                *(u16x4*)&Vtp[((size_t)(b * NKV + (dg >> 6)) * HD + (dg & 63)) * SEQ_ + s] = pk;
            }
        }
    } else {
        int nheads = (mode == 0) ? NH : NKV;
        u16* outp = (mode == 0) ? Qp : Kp;
        float osc = (mode == 0) ? 0.125f * LOG2E : 1.0f;   // fold 1/sqrt(64)*log2e into Q
        int h = (n0 + nh) >> 6;   // 64-col wave-half = one head
        float invf[2];
        #pragma unroll
        for (int p = 0; p < 2; ++p)
            invf[p] = powf(10000.0f, -(float)(16 * p + col) * (1.0f / 32.0f));
        #pragma unroll
        for (int mi = 0; mi < 4; ++mi)
            #pragma unroll
            for (int r = 0; r < 4; ++r) {
                int m = m0 + mh + mi * 16 + l4 * 4 + r;
                int b = m >> 11, s = m & 2047;
                u16* q = outp + ((size_t)(b * nheads + h) * SEQ_ + s) * HD;
                #pragma unroll
                for (int p = 0; p < 2; ++p) {
                    float x0 = acc[mi][p][r] + bcol[p];
                    float x1 = acc[mi][p + 2][r] + bcol[p + 2];
                    float sn, cs;
                    __sincosf((float)s * invf[p], &sn, &cs);
                    q[16 * p + col]      = f2bf((x0 * cs - x1 * sn) * osc);
                    q[16 * p + col + 32] = f2bf((x0 * sn + x1 * cs) * osc);
                }
            }
    }
}

// ---------------- Wo MFMA GEMM: out[M,1024] f32 = Abf[M,1024] * Wob^T ----------------
__global__ __launch_bounds__(256) void gemm_wo(
    const u16* __restrict__ Abf, const u16* __restrict__ Wob, float* __restrict__ out)
{
    __shared__ u16 sA[128 * 32];
    __shared__ u16 sB[128 * 32];
    int tid = threadIdx.x, lane = tid & 63, wave = tid >> 6;
    int col = lane & 15, l4 = lane >> 4;
    int m0 = blockIdx.y * 128, n0 = blockIdx.x * 128;
    int i0 = tid, i1 = tid + 256;
    const u16* ga0 = Abf + (size_t)(m0 + (i0 >> 2)) * HIDDEN + (i0 & 3) * 8;
    const u16* ga1 = Abf + (size_t)(m0 + (i1 >> 2)) * HIDDEN + (i1 & 3) * 8;
    const u16* gb0 = Wob + (size_t)(n0 + (i0 >> 2)) * HIDDEN + (i0 & 3) * 8;
    const u16* gb1 = Wob + (size_t)(n0 + (i1 >> 2)) * HIDDEN + (i1 & 3) * 8;
    u16* la0 = &sA[wave * 512];
    u16* la1 = &sA[2048 + wave * 512];
    u16* lb0 = &sB[wave * 512];
    u16* lb1 = &sB[2048 + wave * 512];

    f32x4 acc[4][4];
    #pragma unroll
    for (int i = 0; i < 4; ++i)
        #pragma unroll
        for (int j = 0; j < 4; ++j) acc[i][j] = (f32x4){0.f, 0.f, 0.f, 0.f};
    int mh = (wave & 1) * 64, nh = (wave >> 1) * 64;

    for (int k0 = 0; k0 < HIDDEN; k0 += 32) {
        __syncthreads();
        async_ld16(ga0, la0); async_ld16(ga1, la1);
        async_ld16(gb0, lb0); async_ld16(gb1, lb1);
        ga0 += 32; ga1 += 32; gb0 += 32; gb1 += 32;
        __syncthreads();
        short8 af[4], bf[4];
        #pragma unroll
        for (int mi = 0; mi < 4; ++mi)
            af[mi] = *(short8*)&sA[(mh + mi * 16 + col) * 32 + l4 * 8];
        #pragma unroll
        for (int ni = 0; ni < 4; ++ni)
            bf[ni] = *(short8*)&sB[(nh + ni * 16 + col) * 32 + l4 * 8];
        #pragma unroll
        for (int mi = 0; mi < 4; ++mi)
            #pragma unroll
            for (int ni = 0; ni < 4; ++ni)
                acc[mi][ni] = __builtin_amdgcn_mfma_f32_16x16x32_bf16(af[mi], bf[ni], acc[mi][ni], 0, 0, 0);
    }
    #pragma unroll
    for (int mi = 0; mi < 4; ++mi)
        #pragma unroll
        for (int r = 0; r < 4; ++r) {
            int m = m0 + mh + mi * 16 + l4 * 4 + r;
            #pragma unroll
            for (int ni = 0; ni < 4; ++ni)
                out[(size_t)m * HIDDEN + n0 + nh + ni * 16 + col] = acc[mi][ni][r];
        }
}

// ---------------- MFMA flash attention v6: 32x32x16 MFMA ----------------
// 128 q/WG, 512 threads = 8 waves: ws = wave&3 (32-q slice), kh = wave>>2 (32-key half).
// S^T = mfma(K, Q): lane owns q = lane&31, 16 keys = (reg&3)+8*(reg>>2)+4*(lane>>5).
// PV as O^T = mfma(V^T, P^T): n = q = same lane. Grid (16, 32) = 512 WGs.
__global__ __launch_bounds__(512, 4) void attn_mfma(
    const u16* __restrict__ Qp, const u16* __restrict__ Kp,
    const u16* __restrict__ Vtp, const float* __restrict__ ams,
    u16* __restrict__ Abf)
{
    __shared__ u16 smem[17408];      // sK[0:4096] sVT[4096:8192] sP[8192:16384]; epilogue overlay 34816B
    u16* sK = smem;
    u16* sVT = smem + 4096;
    int tid = threadIdx.x;
    int lane = tid & 63, wave = tid >> 6;     // 0..7
    int col = lane & 31, h5 = lane >> 5;
    int sx = col & 7;
    int ws = wave & 3, kh = wave >> 2;
    int qb = blockIdx.x, bh = blockIdx.y;
    int b = bh >> 4, h = bh & 15, hk = h >> 2;
    int q0 = qb * 128;
    int qbase = q0 + ws * 32;                 // this wave's 32 queries
    int qcol = qbase + col;
    u16* sPw = smem + 8192 + wave * 1024;     // [q=col][32 keys], 16B-chunk XOR swizzle by col&3

    // Q fragments (B-operand): lane holds Q[q=col][d = ds*16 + h5*8 + j]
    const u16* qp = Qp + ((size_t)(b * NH + h) * SEQ_ + qbase + col) * HD;
    short8 qf[4];
    #pragma unroll
    for (int ds = 0; ds < 4; ++ds)
        qf[ds] = *(const short8*)(qp + ds * 16 + h5 * 8);

    // staging: 512 threads x 16B = 8KB K + 8KB V per round, XOR-swizzled chunks
    int srow = tid >> 3;
    int swc = ((tid & 7) ^ (srow & 7)) * 8;
    const u16* Kbase = Kp + (size_t)(b * NKV + hk) * SEQ_ * HD;
    const u16* Vbase = Vtp + (size_t)(b * NKV + hk) * HD * SEQ_;
    const u16* pK = Kbase + (size_t)srow * HD + swc;
    const u16* pV = Vbase + (size_t)srow * SEQ_ + swc;
    u16* dK = &sK[wave * 512];
    u16* dV = &sVT[wave * 512];

    f32x16 O[2];
    #pragma unroll
    for (int dt = 0; dt < 2; ++dt)
        #pragma unroll
        for (int e = 0; e < 16; ++e) O[dt][e] = 0.f;
    float lsum = 0.f;

    const float* amp = ams + b * SEQ_;
    int nk = min(SEQ_, q0 + 128 + WIN);
    int nkb = (nk + 63) >> 6;

    for (int kb = 0; kb < nkb; ++kb) {
        int k0 = kb * 64;
        __syncthreads();   // prior tile's reads complete
        async_ld16(pK + (size_t)k0 * HD, dK);
        async_ld16(pV + k0, dV);
        __syncthreads();   // DMA landed

        bool dead = (k0 + kh * 32) > (qbase + 31 + WIN);   // wave-uniform
        if (!dead) {
            f32x16 St;
            #pragma unroll
            for (int e = 0; e < 16; ++e) St[e] = 0.f;
            #pragma unroll
            for (int ds = 0; ds < 4; ++ds) {
                short8 kf = *(short8*)&sK[(kh * 32 + col) * 64 + ((ds * 2 + h5) ^ sx) * 8];
                St = __builtin_amdgcn_mfma_f32_32x32x16_bf16(kf, qf[ds], St, 0, 0, 0);
            }
            bool full = (k0 + kh * 32 + 31) <= (qbase + WIN);   // wave-uniform
            float ps = 0.f;
            #pragma unroll
            for (int g = 0; g < 4; ++g) {
                int krow = 8 * g + 4 * h5;
                float4 amv = *(const float4*)(amp + k0 + kh * 32 + krow);
                float amr[4] = {amv.x, amv.y, amv.z, amv.w};
                float pe[4];
                #pragma unroll
                for (int i = 0; i < 4; ++i) {
                    float s = St[g * 4 + i] + amr[i];
                    if (!full) {
                        int kg = k0 + kh * 32 + krow + i;
                        s = (kg - qcol <= WIN) ? s : -INFINITY;
                    }
                    float e = __builtin_amdgcn_exp2f(s);   // scores pre-scaled by log2e
                    pe[i] = e;
                    ps += e;
                }
                uint2 w;
                w.x = pk_trunc(pe[0], pe[1]);
                w.y = pk_trunc(pe[2], pe[3]);
                *(uint2*)&sPw[col * 32 + ((g ^ (col & 3)) * 8) + 4 * h5] = w;
            }
            lsum += ps;
            // P^T B-frags: lane holds P[q=col][key = kstep*16 + h5*8 + j]
            short8 pb0 = *(short8*)&sPw[col * 32 + ((0 * 2 + h5) ^ (col & 3)) * 8];
            short8 pb1 = *(short8*)&sPw[col * 32 + ((1 * 2 + h5) ^ (col & 3)) * 8];
            #pragma unroll
            for (int dt = 0; dt < 2; ++dt) {
                short8 vf0 = *(short8*)&sVT[(dt * 32 + col) * 64 + ((kh * 4 + 0 + h5) ^ sx) * 8];
                O[dt] = __builtin_amdgcn_mfma_f32_32x32x16_bf16(vf0, pb0, O[dt], 0, 0, 0);
                short8 vf1 = *(short8*)&sVT[(dt * 32 + col) * 64 + ((kh * 4 + 2 + h5) ^ sx) * 8];
                O[dt] = __builtin_amdgcn_mfma_f32_32x32x16_bf16(vf1, pb1, O[dt], 0, 0, 0);
            }
        }
    }

    // ---- combine key-halves (kh=0 <- kh=1) through LDS overlay ----
    float l = lsum + __shfl_xor(lsum, 32);   // full 32-key partial for q = col
    __syncthreads();                          // loop reads done; smem reusable
    float* sO = (float*)smem;                 // [ws*32+col][68]: 64 d f32 + lsum at [64]
    int rq = ws * 32 + col;
    if (kh == 1) {
        #pragma unroll
        for (int dt = 0; dt < 2; ++dt)
            #pragma unroll
            for (int g = 0; g < 4; ++g) {
                float4 v = make_float4(O[dt][g * 4 + 0], O[dt][g * 4 + 1],
                                       O[dt][g * 4 + 2], O[dt][g * 4 + 3]);
                *(float4*)&sO[rq * 68 + dt * 32 + 8 * g + 4 * h5] = v;
            }
        if (h5 == 0) sO[rq * 68 + 64] = l;
    }
    __syncthreads();
    if (kh == 0) {
        float linv = 1.0f / (l + sO[rq * 68 + 64]);
        u16* op = Abf + (size_t)(b * SEQ_ + qbase + col) * HIDDEN + h * HD;
        #pragma unroll
        for (int dt = 0; dt < 2; ++dt)
            #pragma unroll
            for (int g = 0; g < 4; ++g) {
                float4 v = *(float4*)&sO[rq * 68 + dt * 32 + 8 * g + 4 * h5];
                u16x4 pk = {f2bf((O[dt][g * 4 + 0] + v.x) * linv),
                            f2bf((O[dt][g * 4 + 1] + v.y) * linv),
                            f2bf((O[dt][g * 4 + 2] + v.z) * linv),
                            f2bf((O[dt][g * 4 + 3] + v.w) * linv)};
                *(u16x4*)(op + dt * 32 + 8 * g + 4 * h5) = pk;
            }
    }
}

extern "C" void kernel_launch(void* const* d_in, const int* in_sizes, int n_in,
                              void* d_out, int out_size, void* d_ws, size_t ws_size,
                              hipStream_t stream) {
    const float* X  = (const float*)d_in[0];
    const float* am = (const float*)d_in[1];
    const float* Wq = (const float*)d_in[2];
    const float* bq = (const float*)d_in[3];
    const float* Wk = (const float*)d_in[4];
    const float* bk = (const float*)d_in[5];
    const float* Wv = (const float*)d_in[6];
    const float* bv = (const float*)d_in[7];
    const float* Wo = (const float*)d_in[8];
    float* out = (float*)d_out;

    const int M = BS_ * SEQ_;            // 4096
    u16* Qp  = (u16*)d_ws;                         // 8 MB
    u16* Kp  = Qp + (size_t)M * HIDDEN;            // 2 MB
    u16* Vtp = Kp + (size_t)M * 256;               // 2 MB
    u16* Xb  = Vtp + (size_t)M * 256;              // 8 MB
    u16* Wqb = Xb + (size_t)M * HIDDEN;            // 2 MB
    u16* Wkb = Wqb + (size_t)HIDDEN * HIDDEN;      // 0.5 MB
    u16* Wvb = Wkb + (size_t)256 * HIDDEN;         // 0.5 MB
    u16* Wob = Wvb + (size_t)256 * HIDDEN;         // 2 MB
    float* ams = (float*)(Wob + (size_t)HIDDEN * HIDDEN);  // 16 KB
    u16* Abf = Xb;  // alias: Xb consumed by gemm_qkv before attn writes Abf

    dim3 blk(256);
    cast6<<<dim3(4096, 6), blk, 0, stream>>>(X, Wq, Wk, Wv, Wo, am, Xb, Wqb, Wkb, Wvb, Wob, ams);
    gemm_qkv<<<dim3(12, 32), blk, 0, stream>>>(Xb, Wqb, Wkb, Wvb, bq, bk, bv, Qp, Kp, Vtp);
    attn_mfma<<<dim3(SEQ_ / 128, BS_ * NH), dim3(512), 0, stream>>>(Qp, Kp, Vtp, ams, Abf);
    gemm_wo<<<dim3(8, 32), blk, 0, stream>>>(Abf, Wob, out);
}

// Round 9
// 205.105 us; speedup vs baseline: 1.0280x; 1.0280x over previous
//
#include <hip/hip_runtime.h>
#include <math.h>

#define HIDDEN 1024
#define NH 16
#define NKV 4
#define HD 64
#define BS_ 2
#define SEQ_ 2048
#define WIN 1534   // allowed iff k - q <= 1534
#define LOG2E 1.4426950408889634f

typedef unsigned short u16;
typedef short short8 __attribute__((ext_vector_type(8)));
typedef float f32x4 __attribute__((ext_vector_type(4)));
typedef float f32x16 __attribute__((ext_vector_type(16)));
typedef u16 u16x4 __attribute__((ext_vector_type(4)));

__device__ __forceinline__ u16 f2bf(float f) {
    unsigned u = __float_as_uint(f);
    u += 0x7fff + ((u >> 16) & 1);      // RNE
    return (u16)(u >> 16);
}

// pack two f32 -> two bf16 (truncation) in ONE v_perm_b32
__device__ __forceinline__ unsigned pk_trunc(float lo, float hi) {
    return __builtin_amdgcn_perm(__float_as_uint(hi), __float_as_uint(lo), 0x07060302u);
}

__device__ __forceinline__ void async_ld16(const u16* g, u16* l) {
    __builtin_amdgcn_global_load_lds(
        (const __attribute__((address_space(1))) unsigned int*)g,
        (__attribute__((address_space(3))) unsigned int*)l, 16, 0, 0);
}

// -------- cast fp32 -> bf16 (X + 4 weights), pre-scale amask, build RoPE LUT --------
__global__ __launch_bounds__(256) void cast6(
    const float* __restrict__ x, const float* __restrict__ wq,
    const float* __restrict__ wk, const float* __restrict__ wv,
    const float* __restrict__ wo, const float* __restrict__ amask,
    u16* __restrict__ xb, u16* __restrict__ wqb, u16* __restrict__ wkb,
    u16* __restrict__ wvb, u16* __restrict__ wob, float* __restrict__ ams,
    float2* __restrict__ rtab)
{
    int seg = blockIdx.y;
    if (seg == 6) {
        int i = blockIdx.x * 256 + threadIdx.x;   // (s, j) over 2048 x 32
        if (i >= SEQ_ * 32) return;
        int s = i >> 5, j = i & 31;
        float inv = powf(10000.0f, -(float)j * (1.0f / 32.0f));
        float sn, cs;
        sincosf((float)s * inv, &sn, &cs);
        rtab[i] = make_float2(cs, sn);
        return;
    }
    int i = (blockIdx.x * 256 + threadIdx.x) * 4;
    if (seg == 5) {
        if (i >= BS_ * SEQ_) return;
        const float sc = -10000.0f * LOG2E;
        float4 v = *(const float4*)(amask + i);
        float4 o = make_float4(v.x * sc, v.y * sc, v.z * sc, v.w * sc);
        *(float4*)(ams + i) = o;
        return;
    }
    const float* srcs[5] = {x, wq, wk, wv, wo};
    u16* dsts[5] = {xb, wqb, wkb, wvb, wob};
    const int ns[5] = {4194304, 1048576, 262144, 262144, 1048576};
    if (i >= ns[seg]) return;
    float4 v = *(const float4*)(srcs[seg] + i);
    u16x4 o = {f2bf(v.x), f2bf(v.y), f2bf(v.z), f2bf(v.w)};
    *(u16x4*)(dsts[seg] + i) = o;
}

// ---------------- fused QKV MFMA GEMM ----------------
// grid (12, 32): bx<8 -> Q, bx<10 -> K, else V. 128x128 tile, BK=32.
// Q: bias+RoPE, pre-scaled by 0.125*log2(e), bf16 head-major [b][h][s][64]
// K: bias+RoPE bf16 head-major; V: bias + bf16 V^T [b][hk][d][SEQ].
__global__ __launch_bounds__(256) void gemm_qkv(
    const u16* __restrict__ Xb, const u16* __restrict__ Wqb,
    const u16* __restrict__ Wkb, const u16* __restrict__ Wvb,
    const float* __restrict__ bq, const float* __restrict__ bk,
    const float* __restrict__ bv, const float2* __restrict__ rtab,
    u16* __restrict__ Qp, u16* __restrict__ Kp, u16* __restrict__ Vtp)
{
    __shared__ u16 sA[128 * 32];
    __shared__ u16 sB[128 * 32];
    int tid = threadIdx.x, lane = tid & 63, wave = tid >> 6;
    int col = lane & 15, l4 = lane >> 4;
    int bx = blockIdx.x, m0 = blockIdx.y * 128;
    const u16* Bsrc; const float* bias; int n0, mode;
    if (bx < 8)       { mode = 0; Bsrc = Wqb; bias = bq; n0 = bx * 128; }
    else if (bx < 10) { mode = 1; Bsrc = Wkb; bias = bk; n0 = (bx - 8) * 128; }
    else              { mode = 2; Bsrc = Wvb; bias = bv; n0 = (bx - 10) * 128; }

    int i0 = tid, i1 = tid + 256;
    const u16* ga0 = Xb + (size_t)(m0 + (i0 >> 2)) * HIDDEN + (i0 & 3) * 8;
    const u16* ga1 = Xb + (size_t)(m0 + (i1 >> 2)) * HIDDEN + (i1 & 3) * 8;
    const u16* gb0 = Bsrc + (size_t)(n0 + (i0 >> 2)) * HIDDEN + (i0 & 3) * 8;
    const u16* gb1 = Bsrc + (size_t)(n0 + (i1 >> 2)) * HIDDEN + (i1 & 3) * 8;
    u16* la0 = &sA[wave * 512];
    u16* la1 = &sA[2048 + wave * 512];
    u16* lb0 = &sB[wave * 512];
    u16* lb1 = &sB[2048 + wave * 512];

    f32x4 acc[4][4];
    #pragma unroll
    for (int i = 0; i < 4; ++i)
        #pragma unroll
        for (int j = 0; j < 4; ++j) acc[i][j] = (f32x4){0.f, 0.f, 0.f, 0.f};
    int mh = (wave & 1) * 64, nh = (wave >> 1) * 64;

    for (int k0 = 0; k0 < HIDDEN; k0 += 32) {
        __syncthreads();
        async_ld16(ga0, la0); async_ld16(ga1, la1);
        async_ld16(gb0, lb0); async_ld16(gb1, lb1);
        ga0 += 32; ga1 += 32; gb0 += 32; gb1 += 32;
        __syncthreads();
        short8 af[4], bf[4];
        #pragma unroll
        for (int mi = 0; mi < 4; ++mi)
            af[mi] = *(short8*)&sA[(mh + mi * 16 + col) * 32 + l4 * 8];
        #pragma unroll
        for (int ni = 0; ni < 4; ++ni)
            bf[ni] = *(short8*)&sB[(nh + ni * 16 + col) * 32 + l4 * 8];
        #pragma unroll
        for (int mi = 0; mi < 4; ++mi)
            #pragma unroll
            for (int ni = 0; ni < 4; ++ni)
                acc[mi][ni] = __builtin_amdgcn_mfma_f32_16x16x32_bf16(af[mi], bf[ni], acc[mi][ni], 0, 0, 0);
    }

    float bcol[4];
    #pragma unroll
    for (int ni = 0; ni < 4; ++ni) bcol[ni] = bias[n0 + nh + ni * 16 + col];

    if (mode == 2) {
        // V^T bf16: [b][hk][d][SEQ]; s contiguous over r -> b64 stores
        #pragma unroll
        for (int mi = 0; mi < 4; ++mi) {
            int m = m0 + mh + mi * 16 + l4 * 4;
            int b = m >> 11, s = m & 2047;
            #pragma unroll
            for (int ni = 0; ni < 4; ++ni) {
                int dg = n0 + nh + ni * 16 + col;
                u16x4 pk = {f2bf(acc[mi][ni][0] + bcol[ni]), f2bf(acc[mi][ni][1] + bcol[ni]),
                            f2bf(acc[mi][ni][2] + bcol[ni]), f2bf(acc[mi][ni][3] + bcol[ni])};
                *(u16x4*)&Vtp[((size_t)(b * NKV + (dg >> 6)) * HD + (dg & 63)) * SEQ_ + s] = pk;
            }
        }
    } else {
        int nheads = (mode == 0) ? NH : NKV;
        u16* outp = (mode == 0) ? Qp : Kp;
        float osc = (mode == 0) ? 0.125f * LOG2E : 1.0f;   // fold 1/sqrt(64)*log2e into Q
        int h = (n0 + nh) >> 6;   // 64-col wave-half = one head
        #pragma unroll
        for (int mi = 0; mi < 4; ++mi)
            #pragma unroll
            for (int r = 0; r < 4; ++r) {
                int m = m0 + mh + mi * 16 + l4 * 4 + r;
                int b = m >> 11, s = m & 2047;
                u16* q = outp + ((size_t)(b * nheads + h) * SEQ_ + s) * HD;
                const float2* tb = rtab + (size_t)s * 32;
                #pragma unroll
                for (int p = 0; p < 2; ++p) {
                    float x0 = acc[mi][p][r] + bcol[p];
                    float x1 = acc[mi][p + 2][r] + bcol[p + 2];
                    float2 cs = tb[16 * p + col];
                    q[16 * p + col]      = f2bf((x0 * cs.x - x1 * cs.y) * osc);
                    q[16 * p + col + 32] = f2bf((x0 * cs.y + x1 * cs.x) * osc);
                }
            }
    }
}

// ---------------- Wo MFMA GEMM: out[M,1024] f32 = Abf[M,1024] * Wob^T ----------------
__global__ __launch_bounds__(256) void gemm_wo(
    const u16* __restrict__ Abf, const u16* __restrict__ Wob, float* __restrict__ out)
{
    __shared__ u16 sA[128 * 32];
    __shared__ u16 sB[128 * 32];
    int tid = threadIdx.x, lane = tid & 63, wave = tid >> 6;
    int col = lane & 15, l4 = lane >> 4;
    int m0 = blockIdx.y * 128, n0 = blockIdx.x * 128;
    int i0 = tid, i1 = tid + 256;
    const u16* ga0 = Abf + (size_t)(m0 + (i0 >> 2)) * HIDDEN + (i0 & 3) * 8;
    const u16* ga1 = Abf + (size_t)(m0 + (i1 >> 2)) * HIDDEN + (i1 & 3) * 8;
    const u16* gb0 = Wob + (size_t)(n0 + (i0 >> 2)) * HIDDEN + (i0 & 3) * 8;
    const u16* gb1 = Wob + (size_t)(n0 + (i1 >> 2)) * HIDDEN + (i1 & 3) * 8;
    u16* la0 = &sA[wave * 512];
    u16* la1 = &sA[2048 + wave * 512];
    u16* lb0 = &sB[wave * 512];
    u16* lb1 = &sB[2048 + wave * 512];

    f32x4 acc[4][4];
    #pragma unroll
    for (int i = 0; i < 4; ++i)
        #pragma unroll
        for (int j = 0; j < 4; ++j) acc[i][j] = (f32x4){0.f, 0.f, 0.f, 0.f};
    int mh = (wave & 1) * 64, nh = (wave >> 1) * 64;

    for (int k0 = 0; k0 < HIDDEN; k0 += 32) {
        __syncthreads();
        async_ld16(ga0, la0); async_ld16(ga1, la1);
        async_ld16(gb0, lb0); async_ld16(gb1, lb1);
        ga0 += 32; ga1 += 32; gb0 += 32; gb1 += 32;
        __syncthreads();
        short8 af[4], bf[4];
        #pragma unroll
        for (int mi = 0; mi < 4; ++mi)
            af[mi] = *(short8*)&sA[(mh + mi * 16 + col) * 32 + l4 * 8];
        #pragma unroll
        for (int ni = 0; ni < 4; ++ni)
            bf[ni] = *(short8*)&sB[(nh + ni * 16 + col) * 32 + l4 * 8];
        #pragma unroll
        for (int mi = 0; mi < 4; ++mi)
            #pragma unroll
            for (int ni = 0; ni < 4; ++ni)
                acc[mi][ni] = __builtin_amdgcn_mfma_f32_16x16x32_bf16(af[mi], bf[ni], acc[mi][ni], 0, 0, 0);
    }
    #pragma unroll
    for (int mi = 0; mi < 4; ++mi)
        #pragma unroll
        for (int r = 0; r < 4; ++r) {
            int m = m0 + mh + mi * 16 + l4 * 4 + r;
            #pragma unroll
            for (int ni = 0; ni < 4; ++ni)
                out[(size_t)m * HIDDEN + n0 + nh + ni * 16 + col] = acc[mi][ni][r];
        }
}

// ---------------- MFMA flash attention v7: 32x32x16, 64 q/WG, 4 waves ----------------
// Grid (32, 32) = 1024 WGs -> 4 WG/CU, 16 waves/CU.
// Wave (ws = wave&1: 32-q slice, kh = wave>>1: 32-key half).
// S^T = mfma(K, Q): lane owns q = lane&31; 16 keys = 8*(reg>>2)+(reg&3)+4*(lane>>5).
// PV as O^T = mfma(V^T, P^T): n = q = same lane. P scratch rows stride 40 u16 (bank-clean).
__global__ __launch_bounds__(256, 4) void attn_mfma(
    const u16* __restrict__ Qp, const u16* __restrict__ Kp,
    const u16* __restrict__ Vtp, const float* __restrict__ ams,
    u16* __restrict__ Abf)
{
    __shared__ u16 smem[13312];      // sK[0:4096] sVT[4096:8192] sP[8192:13312]; overlay 17408B < 26624B
    u16* sK = smem;
    u16* sVT = smem + 4096;
    int tid = threadIdx.x;
    int lane = tid & 63, wave = tid >> 6;     // 0..3
    int col = lane & 31, h5 = lane >> 5;
    int sx = col & 7;
    int ws = wave & 1, kh = wave >> 1;
    int qb = blockIdx.x, bh = blockIdx.y;
    int b = bh >> 4, h = bh & 15, hk = h >> 2;
    int q0 = qb * 64;
    int qbase = q0 + ws * 32;                 // this wave's 32 queries
    int qcol = qbase + col;
    u16* sPw = smem + 8192 + wave * 1280;     // [q=col][32 keys], row stride 40 u16

    // Q fragments (B-operand): lane holds Q[q=qbase+col][d = ds*16 + h5*8 + j]
    const u16* qp = Qp + ((size_t)(b * NH + h) * SEQ_ + qbase + col) * HD;
    short8 qf[4];
    #pragma unroll
    for (int ds = 0; ds < 4; ++ds)
        qf[ds] = *(const short8*)(qp + ds * 16 + h5 * 8);

    // staging: 256 threads x 16B x 2 rounds each for K and V, XOR-swizzled chunks
    int srow = tid >> 3;                       // 0..31 (+32 round 2; row&7 invariant)
    int swc = ((tid & 7) ^ (srow & 7)) * 8;
    const u16* Kbase = Kp + (size_t)(b * NKV + hk) * SEQ_ * HD;
    const u16* Vbase = Vtp + (size_t)(b * NKV + hk) * HD * SEQ_;
    const u16* pK0 = Kbase + (size_t)srow * HD + swc;
    const u16* pK1 = Kbase + (size_t)(srow + 32) * HD + swc;
    const u16* pV0 = Vbase + (size_t)srow * SEQ_ + swc;
    const u16* pV1 = Vbase + (size_t)(srow + 32) * SEQ_ + swc;
    u16* dK0 = &sK[wave * 512];
    u16* dK1 = &sK[2048 + wave * 512];
    u16* dV0 = &sVT[wave * 512];
    u16* dV1 = &sVT[2048 + wave * 512];

    f32x16 O[2];
    #pragma unroll
    for (int dt = 0; dt < 2; ++dt)
        #pragma unroll
        for (int e = 0; e < 16; ++e) O[dt][e] = 0.f;
    float lsum = 0.f;

    const float* amp = ams + b * SEQ_;
    int nk = min(SEQ_, q0 + 64 + WIN);
    int nkb = (nk + 63) >> 6;

    for (int kb = 0; kb < nkb; ++kb) {
        int k0 = kb * 64;
        __syncthreads();   // prior tile's reads complete
        async_ld16(pK0 + (size_t)k0 * HD, dK0);
        async_ld16(pK1 + (size_t)k0 * HD, dK1);
        async_ld16(pV0 + k0, dV0);
        async_ld16(pV1 + k0, dV1);
        __syncthreads();   // DMA landed

        bool dead = (k0 + kh * 32) > (qbase + 31 + WIN);   // wave-uniform
        if (!dead) {
            f32x16 St;
            #pragma unroll
            for (int e = 0; e < 16; ++e) St[e] = 0.f;
            #pragma unroll
            for (int ds = 0; ds < 4; ++ds) {
                short8 kf = *(short8*)&sK[(kh * 32 + col) * 64 + ((ds * 2 + h5) ^ sx) * 8];
                St = __builtin_amdgcn_mfma_f32_32x32x16_bf16(kf, qf[ds], St, 0, 0, 0);
            }
            bool full = (k0 + kh * 32 + 31) <= (qbase + WIN);   // wave-uniform
            float ps = 0.f;
            #pragma unroll
            for (int g = 0; g < 4; ++g) {
                int krow = 8 * g + 4 * h5;
                float4 amv = *(const float4*)(amp + k0 + kh * 32 + krow);
                float amr[4] = {amv.x, amv.y, amv.z, amv.w};
                float pe[4];
                #pragma unroll
                for (int i = 0; i < 4; ++i) {
                    float s = St[g * 4 + i] + amr[i];
                    if (!full) {
                        int kg = k0 + kh * 32 + krow + i;
                        s = (kg - qcol <= WIN) ? s : -INFINITY;
                    }
                    float e = __builtin_amdgcn_exp2f(s);   // scores pre-scaled by log2e
                    pe[i] = e;
                    ps += e;
                }
                uint2 w;
                w.x = pk_trunc(pe[0], pe[1]);
                w.y = pk_trunc(pe[2], pe[3]);
                *(uint2*)&sPw[col * 40 + g * 8 + 4 * h5] = w;   // keys 8g+4h5..+3
            }
            lsum += ps;
            // P^T B-frags: lane holds P[q=col][key = kstep*16 + h5*8 + j]
            short8 pb0 = *(short8*)&sPw[col * 40 + (0 * 2 + h5) * 8];
            short8 pb1 = *(short8*)&sPw[col * 40 + (1 * 2 + h5) * 8];
            #pragma unroll
            for (int dt = 0; dt < 2; ++dt) {
                short8 vf0 = *(short8*)&sVT[(dt * 32 + col) * 64 + ((kh * 4 + 0 + h5) ^ sx) * 8];
                O[dt] = __builtin_amdgcn_mfma_f32_32x32x16_bf16(vf0, pb0, O[dt], 0, 0, 0);
                short8 vf1 = *(short8*)&sVT[(dt * 32 + col) * 64 + ((kh * 4 + 2 + h5) ^ sx) * 8];
                O[dt] = __builtin_amdgcn_mfma_f32_32x32x16_bf16(vf1, pb1, O[dt], 0, 0, 0);
            }
        }
    }

    // ---- combine key-halves (kh=0 <- kh=1) through LDS overlay ----
    float l = lsum + __shfl_xor(lsum, 32);   // full 32-key partial for q = col
    __syncthreads();                          // loop reads done; smem reusable
    float* sO = (float*)smem;                 // [ws*32+col][68]: 64 d f32 + lsum at [64]
    int rq = ws * 32 + col;
    if (kh == 1) {
        #pragma unroll
        for (int dt = 0; dt < 2; ++dt)
            #pragma unroll
            for (int g = 0; g < 4; ++g) {
                float4 v = make_float4(O[dt][g * 4 + 0], O[dt][g * 4 + 1],
                                       O[dt][g * 4 + 2], O[dt][g * 4 + 3]);
                *(float4*)&sO[rq * 68 + dt * 32 + 8 * g + 4 * h5] = v;
            }
        if (h5 == 0) sO[rq * 68 + 64] = l;
    }
    __syncthreads();
    if (kh == 0) {
        float linv = 1.0f / (l + sO[rq * 68 + 64]);
        u16* op = Abf + (size_t)(b * SEQ_ + qbase + col) * HIDDEN + h * HD;
        #pragma unroll
        for (int dt = 0; dt < 2; ++dt)
            #pragma unroll
            for (int g = 0; g < 4; ++g) {
                float4 v = *(float4*)&sO[rq * 68 + dt * 32 + 8 * g + 4 * h5];
                u16x4 pk = {f2bf((O[dt][g * 4 + 0] + v.x) * linv),
                            f2bf((O[dt][g * 4 + 1] + v.y) * linv),
                            f2bf((O[dt][g * 4 + 2] + v.z) * linv),
                            f2bf((O[dt][g * 4 + 3] + v.w) * linv)};
                *(u16x4*)(op + dt * 32 + 8 * g + 4 * h5) = pk;
            }
    }
}

extern "C" void kernel_launch(void* const* d_in, const int* in_sizes, int n_in,
                              void* d_out, int out_size, void* d_ws, size_t ws_size,
                              hipStream_t stream) {
    const float* X  = (const float*)d_in[0];
    const float* am = (const float*)d_in[1];
    const float* Wq = (const float*)d_in[2];
    const float* bq = (const float*)d_in[3];
    const float* Wk = (const float*)d_in[4];
    const float* bk = (const float*)d_in[5];
    const float* Wv = (const float*)d_in[6];
    const float* bv = (const float*)d_in[7];
    const float* Wo = (const float*)d_in[8];
    float* out = (float*)d_out;

    const int M = BS_ * SEQ_;            // 4096
    u16* Qp  = (u16*)d_ws;                         // 8 MB
    u16* Kp  = Qp + (size_t)M * HIDDEN;            // 2 MB
    u16* Vtp = Kp + (size_t)M * 256;               // 2 MB
    u16* Xb  = Vtp + (size_t)M * 256;              // 8 MB
    u16* Wqb = Xb + (size_t)M * HIDDEN;            // 2 MB
    u16* Wkb = Wqb + (size_t)HIDDEN * HIDDEN;      // 0.5 MB
    u16* Wvb = Wkb + (size_t)256 * HIDDEN;         // 0.5 MB
    u16* Wob = Wvb + (size_t)256 * HIDDEN;         // 2 MB
    float* ams = (float*)(Wob + (size_t)HIDDEN * HIDDEN);  // 16 KB
    float2* rtab = (float2*)(ams + BS_ * SEQ_);            // 512 KB RoPE LUT
    u16* Abf = Xb;  // alias: Xb consumed by gemm_qkv before attn writes Abf

    dim3 blk(256);
    cast6<<<dim3(4096, 7), blk, 0, stream>>>(X, Wq, Wk, Wv, Wo, am, Xb, Wqb, Wkb, Wvb, Wob, ams, rtab);
    gemm_qkv<<<dim3(12, 32), blk, 0, stream>>>(Xb, Wqb, Wkb, Wvb, bq, bk, bv, rtab, Qp, Kp, Vtp);
    attn_mfma<<<dim3(SEQ_ / 64, BS_ * NH), blk, 0, stream>>>(Qp, Kp, Vtp, ams, Abf);
    gemm_wo<<<dim3(8, 32), blk, 0, stream>>>(Abf, Wob, out);
}

// Round 10
// 198.797 us; speedup vs baseline: 1.0607x; 1.0317x over previous
//
#include <hip/hip_runtime.h>
#include <math.h>

#define HIDDEN 1024
#define NH 16
#define NKV 4
#define HD 64
#define BS_ 2
#define SEQ_ 2048
#define WIN 1534   // allowed iff k - q <= 1534
#define LOG2E 1.4426950408889634f

typedef unsigned short u16;
typedef short short8 __attribute__((ext_vector_type(8)));
typedef float f32x4 __attribute__((ext_vector_type(4)));
typedef float f32x16 __attribute__((ext_vector_type(16)));
typedef u16 u16x4 __attribute__((ext_vector_type(4)));

__device__ __forceinline__ u16 f2bf(float f) {
    unsigned u = __float_as_uint(f);
    u += 0x7fff + ((u >> 16) & 1);      // RNE
    return (u16)(u >> 16);
}

// pack two f32 -> two bf16 (truncation) in ONE v_perm_b32
__device__ __forceinline__ unsigned pk_trunc(float lo, float hi) {
    return __builtin_amdgcn_perm(__float_as_uint(hi), __float_as_uint(lo), 0x07060302u);
}

__device__ __forceinline__ void async_ld16(const u16* g, u16* l) {
    __builtin_amdgcn_global_load_lds(
        (const __attribute__((address_space(1))) unsigned int*)g,
        (__attribute__((address_space(3))) unsigned int*)l, 16, 0, 0);
}

// -------- cast fp32 -> bf16 (X + 4 weights), pre-scale amask, build RoPE LUT --------
__global__ __launch_bounds__(256) void cast6(
    const float* __restrict__ x, const float* __restrict__ wq,
    const float* __restrict__ wk, const float* __restrict__ wv,
    const float* __restrict__ wo, const float* __restrict__ amask,
    u16* __restrict__ xb, u16* __restrict__ wqb, u16* __restrict__ wkb,
    u16* __restrict__ wvb, u16* __restrict__ wob, float* __restrict__ ams,
    float2* __restrict__ rtab)
{
    int seg = blockIdx.y;
    if (seg == 6) {
        int i = blockIdx.x * 256 + threadIdx.x;   // (s, j) over 2048 x 32
        if (i >= SEQ_ * 32) return;
        int s = i >> 5, j = i & 31;
        float inv = powf(10000.0f, -(float)j * (1.0f / 32.0f));
        float sn, cs;
        sincosf((float)s * inv, &sn, &cs);
        rtab[i] = make_float2(cs, sn);
        return;
    }
    int i = (blockIdx.x * 256 + threadIdx.x) * 4;
    if (seg == 5) {
        if (i >= BS_ * SEQ_) return;
        const float sc = -10000.0f * LOG2E;
        float4 v = *(const float4*)(amask + i);
        float4 o = make_float4(v.x * sc, v.y * sc, v.z * sc, v.w * sc);
        *(float4*)(ams + i) = o;
        return;
    }
    const float* srcs[5] = {x, wq, wk, wv, wo};
    u16* dsts[5] = {xb, wqb, wkb, wvb, wob};
    const int ns[5] = {4194304, 1048576, 262144, 262144, 1048576};
    if (i >= ns[seg]) return;
    float4 v = *(const float4*)(srcs[seg] + i);
    u16x4 o = {f2bf(v.x), f2bf(v.y), f2bf(v.z), f2bf(v.w)};
    *(u16x4*)(dsts[seg] + i) = o;
}

// ---------------- fused QKV MFMA GEMM, 128x64 tile ----------------
// grid (24, 32): bx<16 -> Q, bx<20 -> K, else V. BK=32, 256 thr, wave = 32 rows x 64 cols.
// Q: bias+RoPE, pre-scaled by 0.125*log2(e), bf16 head-major [b][h][s][64]
// K: bias+RoPE bf16 head-major; V: bias + bf16 V^T [b][hk][d][SEQ].
__global__ __launch_bounds__(256) void gemm_qkv(
    const u16* __restrict__ Xb, const u16* __restrict__ Wqb,
    const u16* __restrict__ Wkb, const u16* __restrict__ Wvb,
    const float* __restrict__ bq, const float* __restrict__ bk,
    const float* __restrict__ bv, const float2* __restrict__ rtab,
    u16* __restrict__ Qp, u16* __restrict__ Kp, u16* __restrict__ Vtp)
{
    __shared__ u16 sA[128 * 32];   // 8 KB
    __shared__ u16 sB[64 * 32];    // 4 KB
    int tid = threadIdx.x, lane = tid & 63, wave = tid >> 6;
    int col = lane & 15, l4 = lane >> 4;
    int bx = blockIdx.x, m0 = blockIdx.y * 128;
    const u16* Bsrc; const float* bias; int n0, mode;
    if (bx < 16)      { mode = 0; Bsrc = Wqb; bias = bq; n0 = bx * 64; }
    else if (bx < 20) { mode = 1; Bsrc = Wkb; bias = bk; n0 = (bx - 16) * 64; }
    else              { mode = 2; Bsrc = Wvb; bias = bv; n0 = (bx - 20) * 64; }

    const u16* ga0 = Xb + (size_t)(m0 + (tid >> 2)) * HIDDEN + (tid & 3) * 8;
    const u16* ga1 = Xb + (size_t)(m0 + 64 + (tid >> 2)) * HIDDEN + (tid & 3) * 8;
    const u16* gb0 = Bsrc + (size_t)(n0 + (tid >> 2)) * HIDDEN + (tid & 3) * 8;
    u16* la0 = &sA[wave * 512];
    u16* la1 = &sA[2048 + wave * 512];
    u16* lb0 = &sB[wave * 512];

    f32x4 acc[2][4];
    #pragma unroll
    for (int i = 0; i < 2; ++i)
        #pragma unroll
        for (int j = 0; j < 4; ++j) acc[i][j] = (f32x4){0.f, 0.f, 0.f, 0.f};
    int mh = wave * 32;

    for (int k0 = 0; k0 < HIDDEN; k0 += 32) {
        __syncthreads();
        async_ld16(ga0, la0); async_ld16(ga1, la1); async_ld16(gb0, lb0);
        ga0 += 32; ga1 += 32; gb0 += 32;
        __syncthreads();
        short8 af[2], bf[4];
        #pragma unroll
        for (int mi = 0; mi < 2; ++mi)
            af[mi] = *(short8*)&sA[(mh + mi * 16 + col) * 32 + l4 * 8];
        #pragma unroll
        for (int ni = 0; ni < 4; ++ni)
            bf[ni] = *(short8*)&sB[(ni * 16 + col) * 32 + l4 * 8];
        #pragma unroll
        for (int mi = 0; mi < 2; ++mi)
            #pragma unroll
            for (int ni = 0; ni < 4; ++ni)
                acc[mi][ni] = __builtin_amdgcn_mfma_f32_16x16x32_bf16(af[mi], bf[ni], acc[mi][ni], 0, 0, 0);
    }

    float bcol[4];
    #pragma unroll
    for (int ni = 0; ni < 4; ++ni) bcol[ni] = bias[n0 + ni * 16 + col];

    if (mode == 2) {
        // V^T bf16: [b][hk][d][SEQ]; s contiguous over r -> b64 stores
        #pragma unroll
        for (int mi = 0; mi < 2; ++mi) {
            int m = m0 + mh + mi * 16 + l4 * 4;
            int b = m >> 11, s = m & 2047;
            #pragma unroll
            for (int ni = 0; ni < 4; ++ni) {
                int dg = n0 + ni * 16 + col;
                u16x4 pk = {f2bf(acc[mi][ni][0] + bcol[ni]), f2bf(acc[mi][ni][1] + bcol[ni]),
                            f2bf(acc[mi][ni][2] + bcol[ni]), f2bf(acc[mi][ni][3] + bcol[ni])};
                *(u16x4*)&Vtp[((size_t)(b * NKV + (dg >> 6)) * HD + (dg & 63)) * SEQ_ + s] = pk;
            }
        }
    } else {
        int nheads = (mode == 0) ? NH : NKV;
        u16* outp = (mode == 0) ? Qp : Kp;
        float osc = (mode == 0) ? 0.125f * LOG2E : 1.0f;   // fold 1/sqrt(64)*log2e into Q
        int h = n0 >> 6;   // 64-col tile = one head
        #pragma unroll
        for (int mi = 0; mi < 2; ++mi)
            #pragma unroll
            for (int r = 0; r < 4; ++r) {
                int m = m0 + mh + mi * 16 + l4 * 4 + r;
                int b = m >> 11, s = m & 2047;
                u16* q = outp + ((size_t)(b * nheads + h) * SEQ_ + s) * HD;
                const float2* tb = rtab + (size_t)s * 32;
                #pragma unroll
                for (int p = 0; p < 2; ++p) {
                    float x0 = acc[mi][p][r] + bcol[p];
                    float x1 = acc[mi][p + 2][r] + bcol[p + 2];
                    float2 cs = tb[16 * p + col];
                    q[16 * p + col]      = f2bf((x0 * cs.x - x1 * cs.y) * osc);
                    q[16 * p + col + 32] = f2bf((x0 * cs.y + x1 * cs.x) * osc);
                }
            }
    }
}

// ---------------- Wo MFMA GEMM, 128x64 tile: out[M,1024] f32 = Abf * Wob^T ----------------
__global__ __launch_bounds__(256) void gemm_wo(
    const u16* __restrict__ Abf, const u16* __restrict__ Wob, float* __restrict__ out)
{
    __shared__ u16 sA[128 * 32];
    __shared__ u16 sB[64 * 32];
    int tid = threadIdx.x, lane = tid & 63, wave = tid >> 6;
    int col = lane & 15, l4 = lane >> 4;
    int m0 = blockIdx.y * 128, n0 = blockIdx.x * 64;
    const u16* ga0 = Abf + (size_t)(m0 + (tid >> 2)) * HIDDEN + (tid & 3) * 8;
    const u16* ga1 = Abf + (size_t)(m0 + 64 + (tid >> 2)) * HIDDEN + (tid & 3) * 8;
    const u16* gb0 = Wob + (size_t)(n0 + (tid >> 2)) * HIDDEN + (tid & 3) * 8;
    u16* la0 = &sA[wave * 512];
    u16* la1 = &sA[2048 + wave * 512];
    u16* lb0 = &sB[wave * 512];

    f32x4 acc[2][4];
    #pragma unroll
    for (int i = 0; i < 2; ++i)
        #pragma unroll
        for (int j = 0; j < 4; ++j) acc[i][j] = (f32x4){0.f, 0.f, 0.f, 0.f};
    int mh = wave * 32;

    for (int k0 = 0; k0 < HIDDEN; k0 += 32) {
        __syncthreads();
        async_ld16(ga0, la0); async_ld16(ga1, la1); async_ld16(gb0, lb0);
        ga0 += 32; ga1 += 32; gb0 += 32;
        __syncthreads();
        short8 af[2], bf[4];
        #pragma unroll
        for (int mi = 0; mi < 2; ++mi)
            af[mi] = *(short8*)&sA[(mh + mi * 16 + col) * 32 + l4 * 8];
        #pragma unroll
        for (int ni = 0; ni < 4; ++ni)
            bf[ni] = *(short8*)&sB[(ni * 16 + col) * 32 + l4 * 8];
        #pragma unroll
        for (int mi = 0; mi < 2; ++mi)
            #pragma unroll
            for (int ni = 0; ni < 4; ++ni)
                acc[mi][ni] = __builtin_amdgcn_mfma_f32_16x16x32_bf16(af[mi], bf[ni], acc[mi][ni], 0, 0, 0);
    }
    #pragma unroll
    for (int mi = 0; mi < 2; ++mi)
        #pragma unroll
        for (int r = 0; r < 4; ++r) {
            int m = m0 + mh + mi * 16 + l4 * 4 + r;
            #pragma unroll
            for (int ni = 0; ni < 4; ++ni)
                out[(size_t)m * HIDDEN + n0 + ni * 16 + col] = acc[mi][ni][r];
        }
}

// ---------------- MFMA flash attention v7: 32x32x16, 64 q/WG, 4 waves ----------------
// Grid (32, 32) = 1024 WGs -> 4 WG/CU, 16 waves/CU.
// Wave (ws = wave&1: 32-q slice, kh = wave>>1: 32-key half).
__global__ __launch_bounds__(256, 4) void attn_mfma(
    const u16* __restrict__ Qp, const u16* __restrict__ Kp,
    const u16* __restrict__ Vtp, const float* __restrict__ ams,
    u16* __restrict__ Abf)
{
    __shared__ u16 smem[13312];      // sK[0:4096] sVT[4096:8192] sP[8192:13312]
    u16* sK = smem;
    u16* sVT = smem + 4096;
    int tid = threadIdx.x;
    int lane = tid & 63, wave = tid >> 6;     // 0..3
    int col = lane & 31, h5 = lane >> 5;
    int sx = col & 7;
    int ws = wave & 1, kh = wave >> 1;
    int qb = blockIdx.x, bh = blockIdx.y;
    int b = bh >> 4, h = bh & 15, hk = h >> 2;
    int q0 = qb * 64;
    int qbase = q0 + ws * 32;                 // this wave's 32 queries
    int qcol = qbase + col;
    u16* sPw = smem + 8192 + wave * 1280;     // [q=col][32 keys], row stride 40 u16

    // Q fragments (B-operand): lane holds Q[q=qbase+col][d = ds*16 + h5*8 + j]
    const u16* qp = Qp + ((size_t)(b * NH + h) * SEQ_ + qbase + col) * HD;
    short8 qf[4];
    #pragma unroll
    for (int ds = 0; ds < 4; ++ds)
        qf[ds] = *(const short8*)(qp + ds * 16 + h5 * 8);

    // staging: 256 threads x 16B x 2 rounds each for K and V, XOR-swizzled chunks
    int srow = tid >> 3;
    int swc = ((tid & 7) ^ (srow & 7)) * 8;
    const u16* Kbase = Kp + (size_t)(b * NKV + hk) * SEQ_ * HD;
    const u16* Vbase = Vtp + (size_t)(b * NKV + hk) * HD * SEQ_;
    const u16* pK0 = Kbase + (size_t)srow * HD + swc;
    const u16* pK1 = Kbase + (size_t)(srow + 32) * HD + swc;
    const u16* pV0 = Vbase + (size_t)srow * SEQ_ + swc;
    const u16* pV1 = Vbase + (size_t)(srow + 32) * SEQ_ + swc;
    u16* dK0 = &sK[wave * 512];
    u16* dK1 = &sK[2048 + wave * 512];
    u16* dV0 = &sVT[wave * 512];
    u16* dV1 = &sVT[2048 + wave * 512];

    f32x16 O[2];
    #pragma unroll
    for (int dt = 0; dt < 2; ++dt)
        #pragma unroll
        for (int e = 0; e < 16; ++e) O[dt][e] = 0.f;
    float lsum = 0.f;

    const float* amp = ams + b * SEQ_;
    int nk = min(SEQ_, q0 + 64 + WIN);
    int nkb = (nk + 63) >> 6;

    for (int kb = 0; kb < nkb; ++kb) {
        int k0 = kb * 64;
        __syncthreads();   // prior tile's reads complete
        async_ld16(pK0 + (size_t)k0 * HD, dK0);
        async_ld16(pK1 + (size_t)k0 * HD, dK1);
        async_ld16(pV0 + k0, dV0);
        async_ld16(pV1 + k0, dV1);
        __syncthreads();   // DMA landed

        bool dead = (k0 + kh * 32) > (qbase + 31 + WIN);   // wave-uniform
        if (!dead) {
            f32x16 St;
            #pragma unroll
            for (int e = 0; e < 16; ++e) St[e] = 0.f;
            #pragma unroll
            for (int ds = 0; ds < 4; ++ds) {
                short8 kf = *(short8*)&sK[(kh * 32 + col) * 64 + ((ds * 2 + h5) ^ sx) * 8];
                St = __builtin_amdgcn_mfma_f32_32x32x16_bf16(kf, qf[ds], St, 0, 0, 0);
            }
            bool full = (k0 + kh * 32 + 31) <= (qbase + WIN);   // wave-uniform
            float ps = 0.f;
            #pragma unroll
            for (int g = 0; g < 4; ++g) {
                int krow = 8 * g + 4 * h5;
                float4 amv = *(const float4*)(amp + k0 + kh * 32 + krow);
                float amr[4] = {amv.x, amv.y, amv.z, amv.w};
                float pe[4];
                #pragma unroll
                for (int i = 0; i < 4; ++i) {
                    float s = St[g * 4 + i] + amr[i];
                    if (!full) {
                        int kg = k0 + kh * 32 + krow + i;
                        s = (kg - qcol <= WIN) ? s : -INFINITY;
                    }
                    float e = __builtin_amdgcn_exp2f(s);   // scores pre-scaled by log2e
                    pe[i] = e;
                    ps += e;
                }
                uint2 w;
                w.x = pk_trunc(pe[0], pe[1]);
                w.y = pk_trunc(pe[2], pe[3]);
                *(uint2*)&sPw[col * 40 + g * 8 + 4 * h5] = w;   // keys 8g+4h5..+3
            }
            lsum += ps;
            // P^T B-frags: lane holds P[q=col][key = kstep*16 + h5*8 + j]
            short8 pb0 = *(short8*)&sPw[col * 40 + (0 * 2 + h5) * 8];
            short8 pb1 = *(short8*)&sPw[col * 40 + (1 * 2 + h5) * 8];
            #pragma unroll
            for (int dt = 0; dt < 2; ++dt) {
                short8 vf0 = *(short8*)&sVT[(dt * 32 + col) * 64 + ((kh * 4 + 0 + h5) ^ sx) * 8];
                O[dt] = __builtin_amdgcn_mfma_f32_32x32x16_bf16(vf0, pb0, O[dt], 0, 0, 0);
                short8 vf1 = *(short8*)&sVT[(dt * 32 + col) * 64 + ((kh * 4 + 2 + h5) ^ sx) * 8];
                O[dt] = __builtin_amdgcn_mfma_f32_32x32x16_bf16(vf1, pb1, O[dt], 0, 0, 0);
            }
        }
    }

    // ---- combine key-halves (kh=0 <- kh=1) through LDS overlay ----
    float l = lsum + __shfl_xor(lsum, 32);   // full 32-key partial for q = col
    __syncthreads();                          // loop reads done; smem reusable
    float* sO = (float*)smem;                 // [ws*32+col][68]: 64 d f32 + lsum at [64]
    int rq = ws * 32 + col;
    if (kh == 1) {
        #pragma unroll
        for (int dt = 0; dt < 2; ++dt)
            #pragma unroll
            for (int g = 0; g < 4; ++g) {
                float4 v = make_float4(O[dt][g * 4 + 0], O[dt][g * 4 + 1],
                                       O[dt][g * 4 + 2], O[dt][g * 4 + 3]);
                *(float4*)&sO[rq * 68 + dt * 32 + 8 * g + 4 * h5] = v;
            }
        if (h5 == 0) sO[rq * 68 + 64] = l;
    }
    __syncthreads();
    if (kh == 0) {
        float linv = 1.0f / (l + sO[rq * 68 + 64]);
        u16* op = Abf + (size_t)(b * SEQ_ + qbase + col) * HIDDEN + h * HD;
        #pragma unroll
        for (int dt = 0; dt < 2; ++dt)
            #pragma unroll
            for (int g = 0; g < 4; ++g) {
                float4 v = *(float4*)&sO[rq * 68 + dt * 32 + 8 * g + 4 * h5];
                u16x4 pk = {f2bf((O[dt][g * 4 + 0] + v.x) * linv),
                            f2bf((O[dt][g * 4 + 1] + v.y) * linv),
                            f2bf((O[dt][g * 4 + 2] + v.z) * linv),
                            f2bf((O[dt][g * 4 + 3] + v.w) * linv)};
                *(u16x4*)(op + dt * 32 + 8 * g + 4 * h5) = pk;
            }
    }
}

extern "C" void kernel_launch(void* const* d_in, const int* in_sizes, int n_in,
                              void* d_out, int out_size, void* d_ws, size_t ws_size,
                              hipStream_t stream) {
    const float* X  = (const float*)d_in[0];
    const float* am = (const float*)d_in[1];
    const float* Wq = (const float*)d_in[2];
    const float* bq = (const float*)d_in[3];
    const float* Wk = (const float*)d_in[4];
    const float* bk = (const float*)d_in[5];
    const float* Wv = (const float*)d_in[6];
    const float* bv = (const float*)d_in[7];
    const float* Wo = (const float*)d_in[8];
    float* out = (float*)d_out;

    const int M = BS_ * SEQ_;            // 4096
    u16* Qp  = (u16*)d_ws;                         // 8 MB
    u16* Kp  = Qp + (size_t)M * HIDDEN;            // 2 MB
    u16* Vtp = Kp + (size_t)M * 256;               // 2 MB
    u16* Xb  = Vtp + (size_t)M * 256;              // 8 MB
    u16* Wqb = Xb + (size_t)M * HIDDEN;            // 2 MB
    u16* Wkb = Wqb + (size_t)HIDDEN * HIDDEN;      // 0.5 MB
    u16* Wvb = Wkb + (size_t)256 * HIDDEN;         // 0.5 MB
    u16* Wob = Wvb + (size_t)256 * HIDDEN;         // 2 MB
    float* ams = (float*)(Wob + (size_t)HIDDEN * HIDDEN);  // 16 KB
    float2* rtab = (float2*)(ams + BS_ * SEQ_);            // 512 KB RoPE LUT
    u16* Abf = Xb;  // alias: Xb consumed by gemm_qkv before attn writes Abf

    dim3 blk(256);
    cast6<<<dim3(4096, 7), blk, 0, stream>>>(X, Wq, Wk, Wv, Wo, am, Xb, Wqb, Wkb, Wvb, Wob, ams, rtab);
    gemm_qkv<<<dim3(24, 32), blk, 0, stream>>>(Xb, Wqb, Wkb, Wvb, bq, bk, bv, rtab, Qp, Kp, Vtp);
    attn_mfma<<<dim3(SEQ_ / 64, BS_ * NH), blk, 0, stream>>>(Qp, Kp, Vtp, ams, Abf);
    gemm_wo<<<dim3(16, 32), blk, 0, stream>>>(Abf, Wob, out);
}

// Round 11
// 189.815 us; speedup vs baseline: 1.1109x; 1.0473x over previous
//
#include <hip/hip_runtime.h>
#include <math.h>

#define HIDDEN 1024
#define NH 16
#define NKV 4
#define HD 64
#define BS_ 2
#define SEQ_ 2048
#define WIN 1534   // allowed iff k - q <= 1534
#define LOG2E 1.4426950408889634f

typedef unsigned short u16;
typedef short short8 __attribute__((ext_vector_type(8)));
typedef float f32x4 __attribute__((ext_vector_type(4)));
typedef float f32x16 __attribute__((ext_vector_type(16)));
typedef u16 u16x4 __attribute__((ext_vector_type(4)));

__device__ __forceinline__ u16 f2bf(float f) {
    unsigned u = __float_as_uint(f);
    u += 0x7fff + ((u >> 16) & 1);      // RNE
    return (u16)(u >> 16);
}

// pack two f32 -> two bf16 (truncation) in ONE v_perm_b32
__device__ __forceinline__ unsigned pk_trunc(float lo, float hi) {
    return __builtin_amdgcn_perm(__float_as_uint(hi), __float_as_uint(lo), 0x07060302u);
}

__device__ __forceinline__ void async_ld16(const u16* g, u16* l) {
    __builtin_amdgcn_global_load_lds(
        (const __attribute__((address_space(1))) unsigned int*)g,
        (__attribute__((address_space(3))) unsigned int*)l, 16, 0, 0);
}

// -------- cast fp32 -> bf16 (X + 4 weights), pre-scale amask, build RoPE LUT --------
// Exact-size 1-D grid: 6660 f2bf/amask blocks + 256 rtab blocks = 6916.
#define C_X  1048576
#define C_WQ 1310720
#define C_WK 1376256
#define C_WV 1441792
#define C_WO 1703936
#define C_AM 1704960
__global__ __launch_bounds__(256) void cast6(
    const float* __restrict__ x, const float* __restrict__ wq,
    const float* __restrict__ wk, const float* __restrict__ wv,
    const float* __restrict__ wo, const float* __restrict__ amask,
    u16* __restrict__ xb, u16* __restrict__ wqb, u16* __restrict__ wkb,
    u16* __restrict__ wvb, u16* __restrict__ wob, float* __restrict__ ams,
    float2* __restrict__ rtab)
{
    if (blockIdx.x >= 6660) {
        int i = (blockIdx.x - 6660) * 256 + threadIdx.x;   // (s, j) over 2048 x 32
        int s = i >> 5, j = i & 31;
        float inv = powf(10000.0f, -(float)j * (1.0f / 32.0f));
        float sn, cs;
        sincosf((float)s * inv, &sn, &cs);
        rtab[i] = make_float2(cs, sn);
        return;
    }
    int c = blockIdx.x * 256 + threadIdx.x;   // 4-elem chunk id
    const float* src; u16* dst; int base;
    if (c < C_X)       { src = x;  dst = xb;  base = 0; }
    else if (c < C_WQ) { src = wq; dst = wqb; base = C_X; }
    else if (c < C_WK) { src = wk; dst = wkb; base = C_WQ; }
    else if (c < C_WV) { src = wv; dst = wvb; base = C_WK; }
    else if (c < C_WO) { src = wo; dst = wob; base = C_WV; }
    else {
        int i = (c - C_WO) * 4;
        const float sc = -10000.0f * LOG2E;
        float4 v = *(const float4*)(amask + i);
        *(float4*)(ams + i) = make_float4(v.x * sc, v.y * sc, v.z * sc, v.w * sc);
        return;
    }
    int i = (c - base) * 4;
    float4 v = *(const float4*)(src + i);
    u16x4 o = {f2bf(v.x), f2bf(v.y), f2bf(v.z), f2bf(v.w)};
    *(u16x4*)(dst + i) = o;
}

// ---------------- fused QKV MFMA GEMM, 128x64 tile, XCD-affine mapping ----------------
// 768 blocks 1-D: xcd = id&7 owns by in [4*xcd, 4*xcd+4) x all 24 bx.
// Per-XCD L2 set: A-slice 1MB + B 3MB = 4MB. bx<16 -> Q, bx<20 -> K, else V.
__global__ __launch_bounds__(256) void gemm_qkv(
    const u16* __restrict__ Xb, const u16* __restrict__ Wqb,
    const u16* __restrict__ Wkb, const u16* __restrict__ Wvb,
    const float* __restrict__ bq, const float* __restrict__ bk,
    const float* __restrict__ bv, const float2* __restrict__ rtab,
    u16* __restrict__ Qp, u16* __restrict__ Kp, u16* __restrict__ Vtp)
{
    __shared__ u16 sA[128 * 32];   // 8 KB
    __shared__ u16 sB[64 * 32];    // 4 KB
    int tid = threadIdx.x, lane = tid & 63, wave = tid >> 6;
    int col = lane & 15, l4 = lane >> 4;
    int id = blockIdx.x;
    int xcd = id & 7, slot = id >> 3;
    int by = 4 * xcd + (slot & 3);
    int bx = slot >> 2;              // 0..23
    int m0 = by * 128;
    const u16* Bsrc; const float* bias; int n0, mode;
    if (bx < 16)      { mode = 0; Bsrc = Wqb; bias = bq; n0 = bx * 64; }
    else if (bx < 20) { mode = 1; Bsrc = Wkb; bias = bk; n0 = (bx - 16) * 64; }
    else              { mode = 2; Bsrc = Wvb; bias = bv; n0 = (bx - 20) * 64; }

    const u16* ga0 = Xb + (size_t)(m0 + (tid >> 2)) * HIDDEN + (tid & 3) * 8;
    const u16* ga1 = Xb + (size_t)(m0 + 64 + (tid >> 2)) * HIDDEN + (tid & 3) * 8;
    const u16* gb0 = Bsrc + (size_t)(n0 + (tid >> 2)) * HIDDEN + (tid & 3) * 8;
    u16* la0 = &sA[wave * 512];
    u16* la1 = &sA[2048 + wave * 512];
    u16* lb0 = &sB[wave * 512];

    f32x4 acc[2][4];
    #pragma unroll
    for (int i = 0; i < 2; ++i)
        #pragma unroll
        for (int j = 0; j < 4; ++j) acc[i][j] = (f32x4){0.f, 0.f, 0.f, 0.f};
    int mh = wave * 32;

    for (int k0 = 0; k0 < HIDDEN; k0 += 32) {
        __syncthreads();
        async_ld16(ga0, la0); async_ld16(ga1, la1); async_ld16(gb0, lb0);
        ga0 += 32; ga1 += 32; gb0 += 32;
        __syncthreads();
        short8 af[2], bf[4];
        #pragma unroll
        for (int mi = 0; mi < 2; ++mi)
            af[mi] = *(short8*)&sA[(mh + mi * 16 + col) * 32 + l4 * 8];
        #pragma unroll
        for (int ni = 0; ni < 4; ++ni)
            bf[ni] = *(short8*)&sB[(ni * 16 + col) * 32 + l4 * 8];
        #pragma unroll
        for (int mi = 0; mi < 2; ++mi)
            #pragma unroll
            for (int ni = 0; ni < 4; ++ni)
                acc[mi][ni] = __builtin_amdgcn_mfma_f32_16x16x32_bf16(af[mi], bf[ni], acc[mi][ni], 0, 0, 0);
    }

    float bcol[4];
    #pragma unroll
    for (int ni = 0; ni < 4; ++ni) bcol[ni] = bias[n0 + ni * 16 + col];

    if (mode == 2) {
        // V^T bf16: [b][hk][d][SEQ]; s contiguous over r -> b64 stores
        #pragma unroll
        for (int mi = 0; mi < 2; ++mi) {
            int m = m0 + mh + mi * 16 + l4 * 4;
            int b = m >> 11, s = m & 2047;
            #pragma unroll
            for (int ni = 0; ni < 4; ++ni) {
                int dg = n0 + ni * 16 + col;
                u16x4 pk = {f2bf(acc[mi][ni][0] + bcol[ni]), f2bf(acc[mi][ni][1] + bcol[ni]),
                            f2bf(acc[mi][ni][2] + bcol[ni]), f2bf(acc[mi][ni][3] + bcol[ni])};
                *(u16x4*)&Vtp[((size_t)(b * NKV + (dg >> 6)) * HD + (dg & 63)) * SEQ_ + s] = pk;
            }
        }
    } else {
        int nheads = (mode == 0) ? NH : NKV;
        u16* outp = (mode == 0) ? Qp : Kp;
        float osc = (mode == 0) ? 0.125f * LOG2E : 1.0f;   // fold 1/sqrt(64)*log2e into Q
        int h = n0 >> 6;   // 64-col tile = one head
        #pragma unroll
        for (int mi = 0; mi < 2; ++mi)
            #pragma unroll
            for (int r = 0; r < 4; ++r) {
                int m = m0 + mh + mi * 16 + l4 * 4 + r;
                int b = m >> 11, s = m & 2047;
                u16* q = outp + ((size_t)(b * nheads + h) * SEQ_ + s) * HD;
                const float2* tb = rtab + (size_t)s * 32;
                #pragma unroll
                for (int p = 0; p < 2; ++p) {
                    float x0 = acc[mi][p][r] + bcol[p];
                    float x1 = acc[mi][p + 2][r] + bcol[p + 2];
                    float2 cs = tb[16 * p + col];
                    q[16 * p + col]      = f2bf((x0 * cs.x - x1 * cs.y) * osc);
                    q[16 * p + col + 32] = f2bf((x0 * cs.y + x1 * cs.x) * osc);
                }
            }
    }
}

// ---------------- Wo MFMA GEMM, 128x64 tile, XCD-affine: out = Abf * Wob^T ----------------
// 512 blocks 1-D: xcd = id&7 owns by in [4*xcd, 4*xcd+4) x all 16 bx. Per-XCD: 1MB A + 2MB B.
__global__ __launch_bounds__(256) void gemm_wo(
    const u16* __restrict__ Abf, const u16* __restrict__ Wob, float* __restrict__ out)
{
    __shared__ u16 sA[128 * 32];
    __shared__ u16 sB[64 * 32];
    int tid = threadIdx.x, lane = tid & 63, wave = tid >> 6;
    int col = lane & 15, l4 = lane >> 4;
    int id = blockIdx.x;
    int xcd = id & 7, slot = id >> 3;
    int by = 4 * xcd + (slot & 3);
    int bx = slot >> 2;              // 0..15
    int m0 = by * 128, n0 = bx * 64;
    const u16* ga0 = Abf + (size_t)(m0 + (tid >> 2)) * HIDDEN + (tid & 3) * 8;
    const u16* ga1 = Abf + (size_t)(m0 + 64 + (tid >> 2)) * HIDDEN + (tid & 3) * 8;
    const u16* gb0 = Wob + (size_t)(n0 + (tid >> 2)) * HIDDEN + (tid & 3) * 8;
    u16* la0 = &sA[wave * 512];
    u16* la1 = &sA[2048 + wave * 512];
    u16* lb0 = &sB[wave * 512];

    f32x4 acc[2][4];
    #pragma unroll
    for (int i = 0; i < 2; ++i)
        #pragma unroll
        for (int j = 0; j < 4; ++j) acc[i][j] = (f32x4){0.f, 0.f, 0.f, 0.f};
    int mh = wave * 32;

    for (int k0 = 0; k0 < HIDDEN; k0 += 32) {
        __syncthreads();
        async_ld16(ga0, la0); async_ld16(ga1, la1); async_ld16(gb0, lb0);
        ga0 += 32; ga1 += 32; gb0 += 32;
        __syncthreads();
        short8 af[2], bf[4];
        #pragma unroll
        for (int mi = 0; mi < 2; ++mi)
            af[mi] = *(short8*)&sA[(mh + mi * 16 + col) * 32 + l4 * 8];
        #pragma unroll
        for (int ni = 0; ni < 4; ++ni)
            bf[ni] = *(short8*)&sB[(ni * 16 + col) * 32 + l4 * 8];
        #pragma unroll
        for (int mi = 0; mi < 2; ++mi)
            #pragma unroll
            for (int ni = 0; ni < 4; ++ni)
                acc[mi][ni] = __builtin_amdgcn_mfma_f32_16x16x32_bf16(af[mi], bf[ni], acc[mi][ni], 0, 0, 0);
    }
    #pragma unroll
    for (int mi = 0; mi < 2; ++mi)
        #pragma unroll
        for (int r = 0; r < 4; ++r) {
            int m = m0 + mh + mi * 16 + l4 * 4 + r;
            #pragma unroll
            for (int ni = 0; ni < 4; ++ni)
                out[(size_t)m * HIDDEN + n0 + ni * 16 + col] = acc[mi][ni][r];
        }
}

// ---------------- MFMA flash attention v7.1: 32x32x16, 64 q/WG, incremental pointers ----------------
// Grid (32, 32) = 1024 WGs -> 4 WG/CU, 16 waves/CU.
// Wave (ws = wave&1: 32-q slice, kh = wave>>1: 32-key half).
__global__ __launch_bounds__(256, 4) void attn_mfma(
    const u16* __restrict__ Qp, const u16* __restrict__ Kp,
    const u16* __restrict__ Vtp, const float* __restrict__ ams,
    u16* __restrict__ Abf)
{
    __shared__ u16 smem[13312];      // sK[0:4096] sVT[4096:8192] sP[8192:13312]
    u16* sK = smem;
    u16* sVT = smem + 4096;
    int tid = threadIdx.x;
    int lane = tid & 63, wave = tid >> 6;     // 0..3
    int col = lane & 31, h5 = lane >> 5;
    int sx = col & 7;
    int ws = wave & 1, kh = wave >> 1;
    int qb = blockIdx.x, bh = blockIdx.y;
    int b = bh >> 4, h = bh & 15, hk = h >> 2;
    int q0 = qb * 64;
    int qbase = q0 + ws * 32;                 // this wave's 32 queries
    int qcol = qbase + col;
    u16* sPw = smem + 8192 + wave * 1280;     // [q=col][32 keys], row stride 40 u16

    // Q fragments (B-operand): lane holds Q[q=qbase+col][d = ds*16 + h5*8 + j]
    const u16* qp = Qp + ((size_t)(b * NH + h) * SEQ_ + qbase + col) * HD;
    short8 qf[4];
    #pragma unroll
    for (int ds = 0; ds < 4; ++ds)
        qf[ds] = *(const short8*)(qp + ds * 16 + h5 * 8);

    // staging: 256 threads x 16B x 2 rounds each for K and V, XOR-swizzled chunks
    int srow = tid >> 3;
    int swc = ((tid & 7) ^ (srow & 7)) * 8;
    const u16* pK0 = Kp + (size_t)(b * NKV + hk) * SEQ_ * HD + (size_t)srow * HD + swc;
    const u16* pK1 = pK0 + 32 * HD;
    const u16* pV0 = Vtp + (size_t)(b * NKV + hk) * HD * SEQ_ + (size_t)srow * SEQ_ + swc;
    const u16* pV1 = pV0 + 32 * SEQ_;
    u16* dK0 = &sK[wave * 512];
    u16* dK1 = &sK[2048 + wave * 512];
    u16* dV0 = &sVT[wave * 512];
    u16* dV1 = &sVT[2048 + wave * 512];

    f32x16 O[2];
    #pragma unroll
    for (int dt = 0; dt < 2; ++dt)
        #pragma unroll
        for (int e = 0; e < 16; ++e) O[dt][e] = 0.f;
    float lsum = 0.f;

    const float* ampw = ams + b * SEQ_ + kh * 32 + 4 * h5;
    int nk = min(SEQ_, q0 + 64 + WIN);
    int nkb = (nk + 63) >> 6;

    for (int kb = 0; kb < nkb; ++kb) {
        int k0 = kb * 64;
        __syncthreads();   // prior tile's reads complete
        async_ld16(pK0, dK0);
        async_ld16(pK1, dK1);
        async_ld16(pV0, dV0);
        async_ld16(pV1, dV1);
        pK0 += 64 * HD; pK1 += 64 * HD; pV0 += 64; pV1 += 64;
        __syncthreads();   // DMA landed

        bool dead = (k0 + kh * 32) > (qbase + 31 + WIN);   // wave-uniform
        if (!dead) {
            f32x16 St;
            #pragma unroll
            for (int e = 0; e < 16; ++e) St[e] = 0.f;
            #pragma unroll
            for (int ds = 0; ds < 4; ++ds) {
                short8 kf = *(short8*)&sK[(kh * 32 + col) * 64 + ((ds * 2 + h5) ^ sx) * 8];
                St = __builtin_amdgcn_mfma_f32_32x32x16_bf16(kf, qf[ds], St, 0, 0, 0);
            }
            bool full = (k0 + kh * 32 + 31) <= (qbase + WIN);   // wave-uniform
            float ps = 0.f;
            #pragma unroll
            for (int g = 0; g < 4; ++g) {
                int krow = 8 * g + 4 * h5;
                float4 amv = *(const float4*)(ampw + 8 * g);
                float amr[4] = {amv.x, amv.y, amv.z, amv.w};
                float pe[4];
                #pragma unroll
                for (int i = 0; i < 4; ++i) {
                    float s = St[g * 4 + i] + amr[i];
                    if (!full) {
                        int kg = k0 + kh * 32 + krow + i;
                        s = (kg - qcol <= WIN) ? s : -INFINITY;
                    }
                    float e = __builtin_amdgcn_exp2f(s);   // scores pre-scaled by log2e
                    pe[i] = e;
                    ps += e;
                }
                uint2 w;
                w.x = pk_trunc(pe[0], pe[1]);
                w.y = pk_trunc(pe[2], pe[3]);
                *(uint2*)&sPw[col * 40 + g * 8 + 4 * h5] = w;   // keys 8g+4h5..+3
            }
            lsum += ps;
            // P^T B-frags: lane holds P[q=col][key = kstep*16 + h5*8 + j]
            short8 pb0 = *(short8*)&sPw[col * 40 + (0 * 2 + h5) * 8];
            short8 pb1 = *(short8*)&sPw[col * 40 + (1 * 2 + h5) * 8];
            #pragma unroll
            for (int dt = 0; dt < 2; ++dt) {
                short8 vf0 = *(short8*)&sVT[(dt * 32 + col) * 64 + ((kh * 4 + 0 + h5) ^ sx) * 8];
                O[dt] = __builtin_amdgcn_mfma_f32_32x32x16_bf16(vf0, pb0, O[dt], 0, 0, 0);
                short8 vf1 = *(short8*)&sVT[(dt * 32 + col) * 64 + ((kh * 4 + 2 + h5) ^ sx) * 8];
                O[dt] = __builtin_amdgcn_mfma_f32_32x32x16_bf16(vf1, pb1, O[dt], 0, 0, 0);
            }
        }
        ampw += 64;
    }

    // ---- combine key-halves (kh=0 <- kh=1) through LDS overlay ----
    float l = lsum + __shfl_xor(lsum, 32);   // full 32-key partial for q = col
    __syncthreads();                          // loop reads done; smem reusable
    float* sO = (float*)smem;                 // [ws*32+col][68]: 64 d f32 + lsum at [64]
    int rq = ws * 32 + col;
    if (kh == 1) {
        #pragma unroll
        for (int dt = 0; dt < 2; ++dt)
            #pragma unroll
            for (int g = 0; g < 4; ++g) {
                float4 v = make_float4(O[dt][g * 4 + 0], O[dt][g * 4 + 1],
                                       O[dt][g * 4 + 2], O[dt][g * 4 + 3]);
                *(float4*)&sO[rq * 68 + dt * 32 + 8 * g + 4 * h5] = v;
            }
        if (h5 == 0) sO[rq * 68 + 64] = l;
    }
    __syncthreads();
    if (kh == 0) {
        float linv = 1.0f / (l + sO[rq * 68 + 64]);
        u16* op = Abf + (size_t)(b * SEQ_ + qbase + col) * HIDDEN + h * HD;
        #pragma unroll
        for (int dt = 0; dt < 2; ++dt)
            #pragma unroll
            for (int g = 0; g < 4; ++g) {
                float4 v = *(float4*)&sO[rq * 68 + dt * 32 + 8 * g + 4 * h5];
                u16x4 pk = {f2bf((O[dt][g * 4 + 0] + v.x) * linv),
                            f2bf((O[dt][g * 4 + 1] + v.y) * linv),
                            f2bf((O[dt][g * 4 + 2] + v.z) * linv),
                            f2bf((O[dt][g * 4 + 3] + v.w) * linv)};
                *(u16x4*)(op + dt * 32 + 8 * g + 4 * h5) = pk;
            }
    }
}

extern "C" void kernel_launch(void* const* d_in, const int* in_sizes, int n_in,
                              void* d_out, int out_size, void* d_ws, size_t ws_size,
                              hipStream_t stream) {
    const float* X  = (const float*)d_in[0];
    const float* am = (const float*)d_in[1];
    const float* Wq = (const float*)d_in[2];
    const float* bq = (const float*)d_in[3];
    const float* Wk = (const float*)d_in[4];
    const float* bk = (const float*)d_in[5];
    const float* Wv = (const float*)d_in[6];
    const float* bv = (const float*)d_in[7];
    const float* Wo = (const float*)d_in[8];
    float* out = (float*)d_out;

    const int M = BS_ * SEQ_;            // 4096
    u16* Qp  = (u16*)d_ws;                         // 8 MB
    u16* Kp  = Qp + (size_t)M * HIDDEN;            // 2 MB
    u16* Vtp = Kp + (size_t)M * 256;               // 2 MB
    u16* Xb  = Vtp + (size_t)M * 256;              // 8 MB
    u16* Wqb = Xb + (size_t)M * HIDDEN;            // 2 MB
    u16* Wkb = Wqb + (size_t)HIDDEN * HIDDEN;      // 0.5 MB
    u16* Wvb = Wkb + (size_t)256 * HIDDEN;         // 0.5 MB
    u16* Wob = Wvb + (size_t)256 * HIDDEN;         // 2 MB
    float* ams = (float*)(Wob + (size_t)HIDDEN * HIDDEN);  // 16 KB
    float2* rtab = (float2*)(ams + BS_ * SEQ_);            // 512 KB RoPE LUT
    u16* Abf = Xb;  // alias: Xb consumed by gemm_qkv before attn writes Abf

    dim3 blk(256);
    cast6<<<dim3(6916), blk, 0, stream>>>(X, Wq, Wk, Wv, Wo, am, Xb, Wqb, Wkb, Wvb, Wob, ams, rtab);
    gemm_qkv<<<dim3(768), blk, 0, stream>>>(Xb, Wqb, Wkb, Wvb, bq, bk, bv, rtab, Qp, Kp, Vtp);
    attn_mfma<<<dim3(SEQ_ / 64, BS_ * NH), blk, 0, stream>>>(Qp, Kp, Vtp, ams, Abf);
    gemm_wo<<<dim3(512), blk, 0, stream>>>(Abf, Wob, out);
}